// Round 1
// 2217.831 us; speedup vs baseline: 1.6570x; 1.6570x over previous
//
#include <hip/hip_runtime.h>
#include <stdint.h>

typedef unsigned short u16;
typedef __attribute__((ext_vector_type(8))) short short8;
typedef __attribute__((ext_vector_type(4))) short short4v;
typedef __attribute__((ext_vector_type(4))) float floatx4;

#define SEQ 128
#define BATCH 32
#define NHID 512
#define NVOC 32000
#define LSTM_WGS 64

__device__ __forceinline__ u16 f2bf(float f) {
  uint32_t u;
  __builtin_memcpy(&u, &f, 4);
  uint32_t r = (u + 0x7fffu + ((u >> 16) & 1u)) >> 16;
  return (u16)r;
}
__device__ __forceinline__ short8 cvt8(floatx4 a, floatx4 b) {
  short8 o;
  o[0] = (short)f2bf(a[0]); o[1] = (short)f2bf(a[1]);
  o[2] = (short)f2bf(a[2]); o[3] = (short)f2bf(a[3]);
  o[4] = (short)f2bf(b[0]); o[5] = (short)f2bf(b[1]);
  o[6] = (short)f2bf(b[2]); o[7] = (short)f2bf(b[3]);
  return o;
}

// async global->LDS, 16B per lane (wave-uniform LDS base + lane*16; our chunk
// index is linear in lane so the linear-dest constraint holds)
__device__ __forceinline__ void gload_lds16(const u16* g, u16* l) {
  __builtin_amdgcn_global_load_lds(
      (const __attribute__((address_space(1))) uint32_t*)g,
      (__attribute__((address_space(3))) uint32_t*)l, 16, 0, 0);
}

// -------- embedding gather + fp32->bf16: emb[row][k] = bf16(embW[tok[row]][k]) ----
__global__ void embed_kernel(const int* __restrict__ tok, const float* __restrict__ embW,
                             u16* __restrict__ emb) {
  int row = blockIdx.x;            // 0..4095
  int t = tok[row];
  const floatx4* s = (const floatx4*)(embW + (size_t)t * NHID);
  int i = threadIdx.x;             // 0..63, 8 elems each
  floatx4 a = s[i * 2], b = s[i * 2 + 1];
  ((short8*)(emb + (size_t)row * NHID))[i] = cvt8(a, b);
}

// -------- fp32 -> bf16 bulk convert (for dec_W) --------
__global__ void conv_bf16_kernel(const float* __restrict__ src, u16* __restrict__ dst) {
  int i = blockIdx.x * 256 + threadIdx.x;   // each handles 4 elems
  floatx4 v = ((const floatx4*)src)[i];
  short4v o;
  o[0] = (short)f2bf(v[0]); o[1] = (short)f2bf(v[1]);
  o[2] = (short)f2bf(v[2]); o[3] = (short)f2bf(v[3]);
  ((short4v*)dst)[i] = o;
}

// -------- persistent LSTM --------
// 64 WGs x 256 threads. Wave w: layer = w>>1, units u0 = wg*8 + (w&1)*4.
// A-frags (16 weight rows x 1024 K, fp32->bf16 converted) preloaded in VGPRs once.
// Phase p: layer0 waves compute t=p (p<128); layer1 waves compute t=p-1 (p>=1).
// h0_all/h1_all slot s = h BEFORE step s (slot 0 zeroed); 129 slots of [32][512] bf16.
//
// Barrier redesign (this round): arrive = RELEASE fetch-add (one buffer_wbl2/WG,
// flushes this WG's h stores to LLC); poll = RELAXED sc1 load from LLC (NO
// per-poll buffer_inv — the old ACQUIRE polls invalidated the whole XCD L2 every
// ~64 cy, starving late WGs); exit = single ACQUIRE fence (one buffer_inv) so the
// next phase's h loads refill from LLC.
__global__ __launch_bounds__(256, 1) void lstm_kernel(
    const u16* __restrict__ emb, const float* __restrict__ fcW, const float* __restrict__ fcb,
    u16* __restrict__ h0_all, u16* __restrict__ h1_all, float* __restrict__ hfin,
    int* __restrict__ bar) {
  const int tid  = threadIdx.x;
  const int wave = tid >> 6;
  const int lane = tid & 63;
  const int layer = wave >> 1;
  const int u0 = blockIdx.x * 8 + (wave & 1) * 4;
  const int q  = lane >> 4;     // 0..3
  const int ln = lane & 15;

  // A-operand layout: lane holds A[m=ln][k=q*8+j]; A-row m -> weight row (m&3)*512+u0+(m>>2)
  const int wrow = (ln & 3) * NHID + u0 + (ln >> 2);
  const float* WrowF = fcW + ((size_t)layer * 4 * NHID + (size_t)wrow) * (2 * NHID) + q * 8;
  short8 a_frag[32];
#pragma unroll
  for (int ks = 0; ks < 32; ks++) {
    floatx4 wa = *(const floatx4*)(WrowF + ks * 32);
    floatx4 wb = *(const floatx4*)(WrowF + ks * 32 + 4);
    a_frag[ks] = cvt8(wa, wb);
  }

  // C/D layout: col=ln (batch), row=q*4+reg -> unit uc=u0+q, gate=reg (i,f,o,g)
  const int uc = u0 + q;
  float bias[4];
#pragma unroll
  for (int r = 0; r < 4; r++)
    bias[r] = fcb[layer * 4 * NHID + r * NHID + uc];

  float c_state[2] = {0.f, 0.f};   // per (uc, batch-half)

  for (int p = 0; p <= SEQ; p++) {
    const bool active = (layer == 0) ? (p < SEQ) : (p >= 1);
    if (active) {
      const int t = (layer == 0) ? p : p - 1;
      const u16* srcX = (layer == 0) ? (emb    + (size_t)t       * BATCH * NHID)
                                     : (h0_all + (size_t)(t + 1) * BATCH * NHID);
      const u16* srcH = (layer == 0) ? (h0_all + (size_t)t * BATCH * NHID)
                                     : (h1_all + (size_t)t * BATCH * NHID);
      floatx4 acc[2] = {{0.f,0.f,0.f,0.f},{0.f,0.f,0.f,0.f}};
#pragma unroll
      for (int ks = 0; ks < 16; ks++) {
#pragma unroll
        for (int bt = 0; bt < 2; bt++) {
          short8 bfrag = *(const short8*)(srcX + (size_t)(bt * 16 + ln) * NHID + ks * 32 + q * 8);
          acc[bt] = __builtin_amdgcn_mfma_f32_16x16x32_bf16(a_frag[ks], bfrag, acc[bt], 0, 0, 0);
        }
      }
#pragma unroll
      for (int ks = 16; ks < 32; ks++) {
#pragma unroll
        for (int bt = 0; bt < 2; bt++) {
          short8 bfrag = *(const short8*)(srcH + (size_t)(bt * 16 + ln) * NHID + (ks - 16) * 32 + q * 8);
          acc[bt] = __builtin_amdgcn_mfma_f32_16x16x32_bf16(a_frag[ks], bfrag, acc[bt], 0, 0, 0);
        }
      }
      u16* dst = ((layer == 0) ? h0_all : h1_all) + (size_t)(t + 1) * BATCH * NHID;
#pragma unroll
      for (int bt = 0; bt < 2; bt++) {
        float i_g = 1.f / (1.f + __expf(-(acc[bt][0] + bias[0])));
        float f_g = 1.f / (1.f + __expf(-(acc[bt][1] + bias[1])));
        float o_g = 1.f / (1.f + __expf(-(acc[bt][2] + bias[2])));
        float g_g = tanhf(acc[bt][3] + bias[3]);
        float cn  = f_g * c_state[bt] + i_g * g_g;
        c_state[bt] = cn;
        float h = o_g * tanhf(cn);
        dst[(size_t)(bt * 16 + ln) * NHID + uc] = f2bf(h);
        if (t == SEQ - 1)   // final hidden, fp32, straight to d_out tail
          hfin[((size_t)layer * BATCH + bt * 16 + ln) * NHID + uc] = h;
      }
    }
    if (p < SEQ) {
      __syncthreads();   // all waves' h stores drained to L2 (barrier implies vmcnt(0))
      if (tid == 0) {
        // release RMW: wbl2 flushes this XCD's dirty h lines to LLC, then add@LLC
        __hip_atomic_fetch_add(bar, 1, __ATOMIC_RELEASE, __HIP_MEMORY_SCOPE_AGENT);
        const int target = LSTM_WGS * (p + 1);
        // RELAXED poll: sc1 load straight from LLC, no cache invalidation
        while (__hip_atomic_load(bar, __ATOMIC_RELAXED, __HIP_MEMORY_SCOPE_AGENT) < target)
          __builtin_amdgcn_s_sleep(2);
        // single acquire per phase: invalidate stale clean L1/L2 lines once
        __builtin_amdgcn_fence(__ATOMIC_ACQUIRE, "agent");
      }
      __syncthreads();
    }
  }
}

// -------- decoder GEMM: C[4096][32000] = A[4096][512](bf16) * B[32000][512]^T(bf16) + bias,
// C fp32. m97 structure: 128x128 block tile, BK=64, single-buffered LDS staged via
// global_load_lds (16B/lane), 2 barriers per K-step. 4 waves each own a 64x64
// quadrant (4x4 MFMA frags). K-accumulation order identical to the previous
// direct-global version (bitwise-same output).
// grid.x = M-blocks (32) so consecutive blocks share the same B tile in L2.
__global__ __launch_bounds__(256) void dec_kernel(
    const u16* __restrict__ A, const u16* __restrict__ B,
    const float* __restrict__ bias, float* __restrict__ C) {
  __shared__ u16 lA[128 * 64];   // [row][k] row-major, 16 KB
  __shared__ u16 lB[128 * 64];
  const int tid  = threadIdx.x;
  const int wave = tid >> 6, lane = tid & 63;
  const int wm = wave >> 1, wn = wave & 1;
  const int q = lane >> 4, ln = lane & 15;
  const int mbase = blockIdx.x * 128;
  const int nbase = blockIdx.y * 128;

  floatx4 acc[4][4];
#pragma unroll
  for (int i = 0; i < 4; i++)
#pragma unroll
    for (int j = 0; j < 4; j++) acc[i][j] = (floatx4){0.f, 0.f, 0.f, 0.f};

  // staging decomposition: chunk c = it*256 + tid (1024 chunks of 16B per tile);
  // row = c>>3, col8 = (c&7)*8. LDS byte dest = c*16 — linear in lane within a
  // wave, satisfying global_load_lds's linear-dest constraint.
  const int srow = tid >> 3;          // + it*32
  const int scol = (tid & 7) * 8;

  const u16* Ag = A + (size_t)mbase * 512;
  const u16* Bg = B + (size_t)nbase * 512;

  for (int kt = 0; kt < 8; kt++) {
#pragma unroll
    for (int it = 0; it < 4; it++) {
      const int row = it * 32 + srow;
      gload_lds16(Ag + (size_t)row * 512 + kt * 64 + scol, &lA[row * 64 + scol]);
      gload_lds16(Bg + (size_t)row * 512 + kt * 64 + scol, &lB[row * 64 + scol]);
    }
    asm volatile("s_waitcnt vmcnt(0)" ::: "memory");
    __syncthreads();
#pragma unroll
    for (int ks2 = 0; ks2 < 2; ks2++) {
      short8 af[4], bf[4];
#pragma unroll
      for (int i = 0; i < 4; i++) {
        af[i] = *(const short8*)&lA[(wm * 64 + i * 16 + ln) * 64 + ks2 * 32 + q * 8];
        bf[i] = *(const short8*)&lB[(wn * 64 + i * 16 + ln) * 64 + ks2 * 32 + q * 8];
      }
#pragma unroll
      for (int mt = 0; mt < 4; mt++)
#pragma unroll
        for (int nt = 0; nt < 4; nt++)
          acc[mt][nt] = __builtin_amdgcn_mfma_f32_16x16x32_bf16(af[mt], bf[nt], acc[mt][nt], 0, 0, 0);
    }
    __syncthreads();
  }

  const int mb2 = mbase + wm * 64;
  const int nb2 = nbase + wn * 64;
#pragma unroll
  for (int nt = 0; nt < 4; nt++) {
    const int col = nb2 + nt * 16 + ln;
    const float bv = bias[col];
#pragma unroll
    for (int mt = 0; mt < 4; mt++) {
      const int row0 = mb2 + mt * 16 + q * 4;
#pragma unroll
      for (int r = 0; r < 4; r++)
        C[(size_t)(row0 + r) * NVOC + col] = acc[mt][nt][r] + bv;
    }
  }
}

extern "C" void kernel_launch(void* const* d_in, const int* in_sizes, int n_in,
                              void* d_out, int out_size, void* d_ws, size_t ws_size,
                              hipStream_t stream) {
  const int*   tok  = (const int*)d_in[0];
  const float* embW = (const float*)d_in[1];
  const float* fcW  = (const float*)d_in[2];
  const float* fcb  = (const float*)d_in[3];
  const float* decW = (const float*)d_in[4];
  const float* decb = (const float*)d_in[5];
  float* out = (float*)d_out;

  char* ws = (char*)d_ws;
  const size_t embB = (size_t)SEQ * BATCH * NHID * 2;              // 4 MB
  const size_t hB   = (size_t)(SEQ + 1) * BATCH * NHID * 2;        // ~4.13 MB
  const size_t decB = (size_t)NVOC * NHID * 2;                     // 32.8 MB
  u16* emb     = (u16*)ws;
  u16* h0_all  = (u16*)(ws + embB);
  u16* h1_all  = (u16*)(ws + embB + hB);
  u16* decWbf  = (u16*)(ws + embB + 2 * hB);
  int* bar     = (int*)(ws + embB + 2 * hB + decB);

  hipMemsetAsync(bar, 0, 256, stream);
  hipMemsetAsync(h0_all, 0, (size_t)BATCH * NHID * 2, stream);     // slot 0 = zeros
  hipMemsetAsync(h1_all, 0, (size_t)BATCH * NHID * 2, stream);

  embed_kernel<<<SEQ * BATCH, 64, 0, stream>>>(tok, embW, emb);
  conv_bf16_kernel<<<(NVOC * NHID) / 1024, 256, 0, stream>>>(decW, decWbf);
  lstm_kernel<<<LSTM_WGS, 256, 0, stream>>>(emb, fcW, fcb, h0_all, h1_all,
                                            out + (size_t)SEQ * BATCH * NVOC, bar);
  dec_kernel<<<dim3((SEQ * BATCH) / 128, NVOC / 128), 256, 0, stream>>>(
      h1_all + (size_t)BATCH * NHID, decWbf, decb, out);
}

// Round 3
// 2088.574 us; speedup vs baseline: 1.7595x; 1.0619x over previous
//
#include <hip/hip_runtime.h>
#include <stdint.h>

typedef unsigned short u16;
typedef __attribute__((ext_vector_type(8))) short short8;
typedef __attribute__((ext_vector_type(4))) short short4v;
typedef __attribute__((ext_vector_type(4))) float floatx4;

#define SEQ 128
#define BATCH 32
#define NHID 512
#define NVOC 32000
#define LSTM_WGS 64

__device__ __forceinline__ u16 f2bf(float f) {
  uint32_t u;
  __builtin_memcpy(&u, &f, 4);
  uint32_t r = (u + 0x7fffu + ((u >> 16) & 1u)) >> 16;
  return (u16)r;
}
__device__ __forceinline__ short8 cvt8(floatx4 a, floatx4 b) {
  short8 o;
  o[0] = (short)f2bf(a[0]); o[1] = (short)f2bf(a[1]);
  o[2] = (short)f2bf(a[2]); o[3] = (short)f2bf(a[3]);
  o[4] = (short)f2bf(b[0]); o[5] = (short)f2bf(b[1]);
  o[6] = (short)f2bf(b[2]); o[7] = (short)f2bf(b[3]);
  return o;
}

// async global->LDS, 16B per lane (wave-uniform LDS base + lane*16)
__device__ __forceinline__ void gload_lds16(const u16* g, u16* l) {
  __builtin_amdgcn_global_load_lds(
      (const __attribute__((address_space(1))) uint32_t*)g,
      (__attribute__((address_space(3))) uint32_t*)l, 16, 0, 0);
}

// -------- embedding gather + fp32->bf16 --------
__global__ void embed_kernel(const int* __restrict__ tok, const float* __restrict__ embW,
                             u16* __restrict__ emb) {
  int row = blockIdx.x;            // 0..4095
  int t = tok[row];
  const floatx4* s = (const floatx4*)(embW + (size_t)t * NHID);
  int i = threadIdx.x;             // 0..63, 8 elems each
  floatx4 a = s[i * 2], b = s[i * 2 + 1];
  ((short8*)(emb + (size_t)row * NHID))[i] = cvt8(a, b);
}

// -------- fp32 -> bf16 bulk convert (for dec_W) --------
__global__ void conv_bf16_kernel(const float* __restrict__ src, u16* __restrict__ dst) {
  int i = blockIdx.x * 256 + threadIdx.x;   // each handles 4 elems
  floatx4 v = ((const floatx4*)src)[i];
  short4v o;
  o[0] = (short)f2bf(v[0]); o[1] = (short)f2bf(v[1]);
  o[2] = (short)f2bf(v[2]); o[3] = (short)f2bf(v[3]);
  ((short4v*)dst)[i] = o;
}

// -------- persistent LSTM --------
// 64 WGs x 256 threads. Wave w: layer = w>>1, units u0 = wg*8 + (w&1)*4.
// Layer1 lags by TWO phases (t = p-2) so BOTH layers' x-operand is available
// BEFORE the phase barrier:
//   layer0 @p: x = emb[p],              h = h0_all[p]   (needs wait@p)
//   layer1 @p: x = h0_all[p-1] (stored phase p-2, covered by wait@p-1),
//              h = h1_all[p-2] (stored phase p-1, needs wait@p)
// Phase p: [x-half MFMAs ks0..15] -> [wait: tid0 poll bar>=64p RELAXED +
//   ACQUIRE fence; syncthreads] -> [h-half ks16..31 + epilogue + plain store]
//   -> [syncthreads (drains stores to L2); tid0 RELEASE fetch-add (wbl2->LLC)].
// NOTE (round-2 lesson, HW): sc1 write-through stores + vmcnt(0) + RELAXED add
// is NOT sufficient for cross-XCD visibility on gfx950 — h lines stayed dirty
// in the producer XCD's L2 (absmax 0.018). The wbl2 in the RELEASE RMW is
// required. Protocol below is the round-1-verified one.
__global__ __launch_bounds__(256, 1) void lstm_kernel(
    const u16* __restrict__ emb, const float* __restrict__ fcW, const float* __restrict__ fcb,
    u16* __restrict__ h0_all, u16* __restrict__ h1_all, float* __restrict__ hfin,
    int* __restrict__ bar) {
  const int tid  = threadIdx.x;
  const int wave = tid >> 6;
  const int lane = tid & 63;
  const int layer = wave >> 1;
  const int u0 = blockIdx.x * 8 + (wave & 1) * 4;
  const int q  = lane >> 4;     // 0..3
  const int ln = lane & 15;

  // A-operand layout: lane holds A[m=ln][k=q*8+j]; A-row m -> weight row (m&3)*512+u0+(m>>2)
  const int wrow = (ln & 3) * NHID + u0 + (ln >> 2);
  const float* WrowF = fcW + ((size_t)layer * 4 * NHID + (size_t)wrow) * (2 * NHID) + q * 8;
  short8 a_frag[32];
#pragma unroll
  for (int ks = 0; ks < 32; ks++) {
    floatx4 wa = *(const floatx4*)(WrowF + ks * 32);
    floatx4 wb = *(const floatx4*)(WrowF + ks * 32 + 4);
    a_frag[ks] = cvt8(wa, wb);
  }

  // C/D layout: col=ln (batch), row=q*4+reg -> unit uc=u0+q, gate=reg (i,f,o,g)
  const int uc = u0 + q;
  float bias[4];
#pragma unroll
  for (int r = 0; r < 4; r++)
    bias[r] = fcb[layer * 4 * NHID + r * NHID + uc];

  float c_state[2] = {0.f, 0.f};   // per (uc, batch-half)

  for (int p = 0; p <= SEQ + 1; p++) {            // 130 phases
    const int t = (layer == 0) ? p : p - 2;
    const bool act = (t >= 0) && (t < SEQ);
    floatx4 acc[2] = {{0.f,0.f,0.f,0.f},{0.f,0.f,0.f,0.f}};

    // ---- x-half (pre-barrier available): ks 0..15 ----
    if (act) {
      const u16* srcX = (layer == 0) ? (emb    + (size_t)t       * BATCH * NHID)
                                     : (h0_all + (size_t)(t + 1) * BATCH * NHID);
#pragma unroll
      for (int ks = 0; ks < 16; ks++) {
#pragma unroll
        for (int bt = 0; bt < 2; bt++) {
          short8 bfrag = *(const short8*)(srcX + (size_t)(bt * 16 + ln) * NHID + ks * 32 + q * 8);
          acc[bt] = __builtin_amdgcn_mfma_f32_16x16x32_bf16(a_frag[ks], bfrag, acc[bt], 0, 0, 0);
        }
      }
    }

    // ---- wait for barrier p-1 (h stores of previous phase released to LLC) ----
    if (p >= 1) {
      if (tid == 0) {
        const int target = LSTM_WGS * p;
        while (__hip_atomic_load(bar, __ATOMIC_RELAXED, __HIP_MEMORY_SCOPE_AGENT) < target)
          __builtin_amdgcn_s_sleep(2);
        // one inv per phase: drop stale clean L1/L2 lines; fresh data is at LLC
        __builtin_amdgcn_fence(__ATOMIC_ACQUIRE, "agent");
      }
      __syncthreads();
    }

    // ---- h-half (ks 16..31) + epilogue + h store ----
    if (act) {
      const u16* srcH = (layer == 0) ? (h0_all + (size_t)t * BATCH * NHID)
                                     : (h1_all + (size_t)t * BATCH * NHID);
#pragma unroll
      for (int ks = 16; ks < 32; ks++) {
#pragma unroll
        for (int bt = 0; bt < 2; bt++) {
          short8 bfrag = *(const short8*)(srcH + (size_t)(bt * 16 + ln) * NHID + (ks - 16) * 32 + q * 8);
          acc[bt] = __builtin_amdgcn_mfma_f32_16x16x32_bf16(a_frag[ks], bfrag, acc[bt], 0, 0, 0);
        }
      }
      u16* dst = ((layer == 0) ? h0_all : h1_all) + (size_t)(t + 1) * BATCH * NHID;
#pragma unroll
      for (int bt = 0; bt < 2; bt++) {
        float i_g = 1.f / (1.f + __expf(-(acc[bt][0] + bias[0])));
        float f_g = 1.f / (1.f + __expf(-(acc[bt][1] + bias[1])));
        float o_g = 1.f / (1.f + __expf(-(acc[bt][2] + bias[2])));
        float g_g = tanhf(acc[bt][3] + bias[3]);
        float cn  = f_g * c_state[bt] + i_g * g_g;
        c_state[bt] = cn;
        float h = o_g * tanhf(cn);
        dst[(size_t)(bt * 16 + ln) * NHID + uc] = f2bf(h);
        if (t == SEQ - 1)   // final hidden, fp32, straight to d_out tail
          hfin[((size_t)layer * BATCH + bt * 16 + ln) * NHID + uc] = h;
      }
    }

    // ---- arrive (phases 0..SEQ) ----
    if (p <= SEQ) {
      __syncthreads();   // implies vmcnt(0): all 4 waves' stores drained to L2
      if (tid == 0)      // RELEASE RMW: wbl2 flushes this XCD's dirty h lines to LLC
        __hip_atomic_fetch_add(bar, 1, __ATOMIC_RELEASE, __HIP_MEMORY_SCOPE_AGENT);
    }
  }
}

// -------- decoder GEMM: C[4096][32000] = A[4096][512](bf16) * B[32000][512]^T(bf16) + bias.
// Double-buffered LDS (T3/T4 minimum recipe): issue next tile's global_load_lds BEFORE
// waiting, counted s_waitcnt vmcnt(8) (own prev-tile loads done) -> raw s_barrier ->
// compute. Loads stay in flight across barriers; vmcnt never drains to 0 mid-loop.
__global__ __launch_bounds__(256) void dec_kernel(
    const u16* __restrict__ A, const u16* __restrict__ B,
    const float* __restrict__ bias, float* __restrict__ C) {
  __shared__ u16 lA[2][128 * 64];   // 2 x 16 KB
  __shared__ u16 lB[2][128 * 64];
  const int tid  = threadIdx.x;
  const int wave = tid >> 6, lane = tid & 63;
  const int wm = wave >> 1, wn = wave & 1;
  const int q = lane >> 4, ln = lane & 15;
  const int mbase = blockIdx.x * 128;
  const int nbase = blockIdx.y * 128;

  floatx4 acc[4][4];
#pragma unroll
  for (int i = 0; i < 4; i++)
#pragma unroll
    for (int j = 0; j < 4; j++) acc[i][j] = (floatx4){0.f, 0.f, 0.f, 0.f};

  // staging: per-lane LDS dest = wave-base + lane*16 (linear, gload_lds-safe)
  const int srow = tid >> 3;          // + it*32
  const int scol = (tid & 7) * 8;

  const u16* Ag = A + (size_t)mbase * 512;
  const u16* Bg = B + (size_t)nbase * 512;

  // prologue: stage tile 0 into buf 0 (8 loads/wave)
#pragma unroll
  for (int it = 0; it < 4; it++) {
    const int row = it * 32 + srow;
    gload_lds16(Ag + (size_t)row * 512 + scol, &lA[0][row * 64 + scol]);
    gload_lds16(Bg + (size_t)row * 512 + scol, &lB[0][row * 64 + scol]);
  }

  for (int kt = 0; kt < 8; kt++) {
    const int cur = kt & 1;
    if (kt < 7) {   // stage tile kt+1 into other buffer, then wait only own tile-kt loads
#pragma unroll
      for (int it = 0; it < 4; it++) {
        const int row = it * 32 + srow;
        gload_lds16(Ag + (size_t)row * 512 + (kt + 1) * 64 + scol, &lA[cur ^ 1][row * 64 + scol]);
        gload_lds16(Bg + (size_t)row * 512 + (kt + 1) * 64 + scol, &lB[cur ^ 1][row * 64 + scol]);
      }
      asm volatile("s_waitcnt vmcnt(8)" ::: "memory");   // 8 newest (kt+1) may stay in flight
    } else {
      asm volatile("s_waitcnt vmcnt(0)" ::: "memory");
    }
    __builtin_amdgcn_s_barrier();     // all waves' tile-kt loads complete
    asm volatile("" ::: "memory");
#pragma unroll
    for (int ks2 = 0; ks2 < 2; ks2++) {
      short8 af[4], bf[4];
#pragma unroll
      for (int i = 0; i < 4; i++) {
        af[i] = *(const short8*)&lA[cur][(wm * 64 + i * 16 + ln) * 64 + ks2 * 32 + q * 8];
        bf[i] = *(const short8*)&lB[cur][(wn * 64 + i * 16 + ln) * 64 + ks2 * 32 + q * 8];
      }
#pragma unroll
      for (int mt = 0; mt < 4; mt++)
#pragma unroll
        for (int nt = 0; nt < 4; nt++)
          acc[mt][nt] = __builtin_amdgcn_mfma_f32_16x16x32_bf16(af[mt], bf[nt], acc[mt][nt], 0, 0, 0);
    }
    asm volatile("" ::: "memory");
    __builtin_amdgcn_s_barrier();     // reads of buf cur done before it's overwritten
  }

  const int mb2 = mbase + wm * 64;
  const int nb2 = nbase + wn * 64;
#pragma unroll
  for (int nt = 0; nt < 4; nt++) {
    const int col = nb2 + nt * 16 + ln;
    const float bv = bias[col];
#pragma unroll
    for (int mt = 0; mt < 4; mt++) {
      const int row0 = mb2 + mt * 16 + q * 4;
#pragma unroll
      for (int r = 0; r < 4; r++)
        C[(size_t)(row0 + r) * NVOC + col] = acc[mt][nt][r] + bv;
    }
  }
}

extern "C" void kernel_launch(void* const* d_in, const int* in_sizes, int n_in,
                              void* d_out, int out_size, void* d_ws, size_t ws_size,
                              hipStream_t stream) {
  const int*   tok  = (const int*)d_in[0];
  const float* embW = (const float*)d_in[1];
  const float* fcW  = (const float*)d_in[2];
  const float* fcb  = (const float*)d_in[3];
  const float* decW = (const float*)d_in[4];
  const float* decb = (const float*)d_in[5];
  float* out = (float*)d_out;

  char* ws = (char*)d_ws;
  const size_t embB = (size_t)SEQ * BATCH * NHID * 2;              // 4 MB
  const size_t hB   = (size_t)(SEQ + 1) * BATCH * NHID * 2;        // ~4.13 MB
  const size_t decB = (size_t)NVOC * NHID * 2;                     // 32.8 MB
  u16* emb     = (u16*)ws;
  u16* h0_all  = (u16*)(ws + embB);
  u16* h1_all  = (u16*)(ws + embB + hB);
  u16* decWbf  = (u16*)(ws + embB + 2 * hB);
  int* bar     = (int*)(ws + embB + 2 * hB + decB);

  hipMemsetAsync(bar, 0, 256, stream);
  hipMemsetAsync(h0_all, 0, (size_t)BATCH * NHID * 2, stream);     // slot 0 = zeros
  hipMemsetAsync(h1_all, 0, (size_t)BATCH * NHID * 2, stream);

  embed_kernel<<<SEQ * BATCH, 64, 0, stream>>>(tok, embW, emb);
  conv_bf16_kernel<<<(NVOC * NHID) / 1024, 256, 0, stream>>>(decW, decWbf);
  lstm_kernel<<<LSTM_WGS, 256, 0, stream>>>(emb, fcW, fcb, h0_all, h1_all,
                                            out + (size_t)SEQ * BATCH * NVOC, bar);
  dec_kernel<<<dim3((SEQ * BATCH) / 128, NVOC / 128), 256, 0, stream>>>(
      h1_all + (size_t)BATCH * NHID, decWbf, decb, out);
}